// Round 1
// baseline (511.393 us; speedup 1.0000x reference)
//
#include <hip/hip_runtime.h>
#include <hip/hip_bf16.h>

// VecLocal2d: x[320][32][32][32] f32, weight[32][32][64][288] f32, bias[10][64][1024] f32
// out[320][64][1024] f32.  Per (h,w): out[m,o] = sum_k patch[m,k]*W[o,k] + bias.
//
// Strategy: pre-transpose x -> xT[c][y][xc][m] bf16 (d_ws, 21 MB) so patch staging is
// coalesced; one block per (h,w) location does the 320x64x288 GEMM with
// mfma_f32_16x16x32_bf16, weight staged once to LDS (B-frags then live in VGPRs).

typedef __attribute__((ext_vector_type(8))) short short8;
typedef __attribute__((ext_vector_type(4))) float f32x4;
typedef __attribute__((ext_vector_type(4))) unsigned short ushort4b;

#define XT_ELEMS 10485760  // 32*32*32*320

__device__ __forceinline__ unsigned short f2bf(float f) {
    __hip_bfloat16 b = __float2bfloat16(f);
    return __builtin_bit_cast(unsigned short, b);
}

// ---- kernel 1: x[m][i] f32 -> xT[i][m] bf16, i = c*1024 + y*32 + xc (320 x 32768 transpose)
__global__ __launch_bounds__(256) void VecLocal2d_xpose(const float* __restrict__ x,
                                                        unsigned short* __restrict__ xT) {
    __shared__ unsigned short tile[64][66];  // 66: bank-spread pad (33 dw stride -> 2-way, free)
    const int ib = blockIdx.x % 512;  // inner-dim tile (32768/64)
    const int mb = blockIdx.x / 512;  // m tile (320/64)
    const int il = threadIdx.x & 63;
    const int t4 = threadIdx.x >> 6;
#pragma unroll
    for (int p = 0; p < 16; ++p) {
        const int ml = t4 + p * 4;
        const float v = x[(size_t)(mb * 64 + ml) * 32768 + ib * 64 + il];
        tile[ml][il] = f2bf(v);
    }
    __syncthreads();
#pragma unroll
    for (int p = 0; p < 16; ++p) {
        const int iw = t4 + p * 4;
        xT[(size_t)(ib * 64 + iw) * 320 + mb * 64 + il] = tile[il][iw];
    }
}

// ---- kernel 2: main GEMM per location
__global__ __launch_bounds__(256, 2) void VecLocal2d_main(const unsigned short* __restrict__ xT,
                                                          const float* __restrict__ weight,
                                                          const float* __restrict__ bias,
                                                          float* __restrict__ out) {
    __shared__ unsigned short wLDS[64 * 296];  // [o][k], k = c*9+p*3+q, pad 288->296
    __shared__ unsigned short pLDS[64 * 296];  // [m][k]

    // XCD swizzle: blocks with same (h, w-octet) share bid%8 -> same XCD (store-line merge,
    // xT L2 reuse). bid = s*128 + h*4 + g, w = g*8 + s.
    const int bid = blockIdx.x;
    const int s = bid >> 7;
    const int hg = bid & 127;
    const int h = hg >> 2;
    const int w = ((hg & 3) << 3) | s;
    const int loc = h * 32 + w;

    const int tid = threadIdx.x;
    const int lane = tid & 63;
    const int wave = tid >> 6;
    const int quad = lane >> 4;
    const int l16 = lane & 15;
    const int wm = wave >> 1, wn = wave & 1;  // 2x2 wave grid over (m32, o32)

    // ---- stage weight (64*288 f32, contiguous) -> wLDS bf16 ----
    const float* wg = weight + (size_t)loc * 18432;
#pragma unroll
    for (int i = 0; i < 18; ++i) {
        const int f4i = tid + i * 256;  // 0..4607 float4s
        const float4 v = reinterpret_cast<const float4*>(wg)[f4i];
        const int o = f4i / 72;
        const int k4 = (f4i - o * 72) * 4;
        ushort4b u;
        u.x = f2bf(v.x); u.y = f2bf(v.y); u.z = f2bf(v.z); u.w = f2bf(v.w);
        *reinterpret_cast<ushort4b*>(&wLDS[o * 296 + k4]) = u;
    }

    // ---- precompute xT offsets for this thread's 72 k's (validity folded to zero-row) ----
    int xoff[18][4];
#pragma unroll
    for (int j = 0; j < 18; ++j) {
        const int kq = wave + 4 * j;
#pragma unroll
        for (int ii = 0; ii < 4; ++ii) {
            const int k = kq * 4 + ii;
            const int c = k / 9;
            const int r9 = k - c * 9;
            const int yy = r9 / 3;
            const int q = r9 - yy * 3;
            const int y = h - 1 + yy;
            const int xc = w - 1 + q;
            const bool valid = ((unsigned)y < 32u) && ((unsigned)xc < 32u);
            const int off = valid ? ((c * 32 + y) * 32 + xc) * 320 : XT_ELEMS;
            xoff[j][ii] = off + lane;
        }
    }

    __syncthreads();

    // ---- B-fragments live in registers for the whole m-loop (weight read once) ----
    short8 bfr[2][9];
#pragma unroll
    for (int tni = 0; tni < 2; ++tni) {
        const int o = (wn * 2 + tni) * 16 + l16;
#pragma unroll
        for (int kt = 0; kt < 9; ++kt)
            bfr[tni][kt] = *reinterpret_cast<const short8*>(&wLDS[o * 296 + kt * 32 + quad * 8]);
    }

    for (int mt = 0; mt < 5; ++mt) {
        const int mb = mt * 64;
        __syncthreads();  // pLDS WAR vs previous iteration's A-frag reads
        // stage patches: wave covers kq = wave+4j, lanes = m rows; 128B-coalesced xT reads
#pragma unroll
        for (int j = 0; j < 18; ++j) {
            ushort4b u;
            u.x = xT[xoff[j][0] + mb];
            u.y = xT[xoff[j][1] + mb];
            u.z = xT[xoff[j][2] + mb];
            u.w = xT[xoff[j][3] + mb];
            const int kq = wave + 4 * j;
            *reinterpret_cast<ushort4b*>(&pLDS[lane * 296 + kq * 4]) = u;
        }
        __syncthreads();

        f32x4 acc[2][2] = {};
#pragma unroll
        for (int kt = 0; kt < 9; ++kt) {
            const short8 a0 = *reinterpret_cast<const short8*>(
                &pLDS[((wm * 2 + 0) * 16 + l16) * 296 + kt * 32 + quad * 8]);
            const short8 a1 = *reinterpret_cast<const short8*>(
                &pLDS[((wm * 2 + 1) * 16 + l16) * 296 + kt * 32 + quad * 8]);
            acc[0][0] = __builtin_amdgcn_mfma_f32_16x16x32_bf16(a0, bfr[0][kt], acc[0][0], 0, 0, 0);
            acc[0][1] = __builtin_amdgcn_mfma_f32_16x16x32_bf16(a0, bfr[1][kt], acc[0][1], 0, 0, 0);
            acc[1][0] = __builtin_amdgcn_mfma_f32_16x16x32_bf16(a1, bfr[0][kt], acc[1][0], 0, 0, 0);
            acc[1][1] = __builtin_amdgcn_mfma_f32_16x16x32_bf16(a1, bfr[1][kt], acc[1][1], 0, 0, 0);
        }

        // D layout: row m = quad*4 + r, col o = l16 (m89/m91-verified)
#pragma unroll
        for (int tmi = 0; tmi < 2; ++tmi)
#pragma unroll
            for (int tni = 0; tni < 2; ++tni) {
                const int o = (wn * 2 + tni) * 16 + l16;
#pragma unroll
                for (int r = 0; r < 4; ++r) {
                    const int m = mb + (wm * 2 + tmi) * 16 + quad * 4 + r;
                    const int cat = m % 10;
                    const float bv = bias[(size_t)(cat * 64 + o) * 1024 + loc];
                    out[(size_t)(m * 64 + o) * 1024 + loc] = acc[tmi][tni][r] + bv;
                }
            }
    }
}

extern "C" void kernel_launch(void* const* d_in, const int* in_sizes, int n_in,
                              void* d_out, int out_size, void* d_ws, size_t ws_size,
                              hipStream_t stream) {
    const float* x = (const float*)d_in[0];
    const float* wgt = (const float*)d_in[1];
    const float* bias = (const float*)d_in[2];
    float* out = (float*)d_out;
    unsigned short* xT = (unsigned short*)d_ws;  // needs 21.0 MB (+768 B zero pad)

    // zero row for out-of-bounds patch taps (d_ws is re-poisoned before every launch)
    hipMemsetAsync(xT + XT_ELEMS, 0, 384 * sizeof(unsigned short), stream);
    VecLocal2d_xpose<<<2560, 256, 0, stream>>>(x, xT);
    VecLocal2d_main<<<1024, 256, 0, stream>>>(xT, wgt, bias, out);
}

// Round 2
// 247.510 us; speedup vs baseline: 2.0661x; 2.0661x over previous
//
#include <hip/hip_runtime.h>
#include <hip/hip_bf16.h>

// VecLocal2d: x[320][32][32][32] f32, weight[32][32][64][288] f32, bias[10][64][1024] f32
// out[320][64][1024] f32.  Per (h,w): out[m,o] = sum_k patch[m,k]*W[o,k] + bias.
//
// R2: main kernel stores to out_s[loc][m][o] (contiguous 80 KB/block, full-line writes)
// instead of scattered 4B stores into out[mo][loc] (which cost 537 MB WRITE_SIZE + RFO).
// New outT kernel transposes out_s -> out with bias fused (all traffic float4-coalesced).

typedef __attribute__((ext_vector_type(8))) short short8;
typedef __attribute__((ext_vector_type(4))) float f32x4;
typedef __attribute__((ext_vector_type(4))) unsigned short ushort4b;

#define XT_ELEMS 10485760              // 32*32*32*320
#define OUTS_OFF_BYTES 20972544        // xT (20,971,520 B) + 1 KB pad, 16B-aligned

__device__ __forceinline__ unsigned short f2bf(float f) {
    __hip_bfloat16 b = __float2bfloat16(f);
    return __builtin_bit_cast(unsigned short, b);
}

// ---- kernel 1: x[m][i] f32 -> xT[i][m] bf16, i = c*1024 + y*32 + xc (320 x 32768 transpose)
__global__ __launch_bounds__(256) void VecLocal2d_xpose(const float* __restrict__ x,
                                                        unsigned short* __restrict__ xT) {
    __shared__ unsigned short tile[64][66];
    // zero-pad row for out-of-bounds patch taps (d_ws re-poisoned every launch)
    if (blockIdx.x == 0 && threadIdx.x < 192)
        reinterpret_cast<unsigned int*>(xT + XT_ELEMS)[threadIdx.x] = 0u;
    const int ib = blockIdx.x % 512;  // inner-dim tile (32768/64)
    const int mb = blockIdx.x / 512;  // m tile (320/64)
    const int il = threadIdx.x & 63;
    const int t4 = threadIdx.x >> 6;
#pragma unroll
    for (int p = 0; p < 16; ++p) {
        const int ml = t4 + p * 4;
        const float v = x[(size_t)(mb * 64 + ml) * 32768 + ib * 64 + il];
        tile[ml][il] = f2bf(v);
    }
    __syncthreads();
#pragma unroll
    for (int p = 0; p < 16; ++p) {
        const int iw = t4 + p * 4;
        xT[(size_t)(ib * 64 + iw) * 320 + mb * 64 + il] = tile[il][iw];
    }
}

// ---- kernel 2: main GEMM per location, writes out_s[loc][m][o]
__global__ __launch_bounds__(256, 2) void VecLocal2d_main(const unsigned short* __restrict__ xT,
                                                          const float* __restrict__ weight,
                                                          float* __restrict__ out_s) {
    __shared__ unsigned short wLDS[64 * 296];  // [o][k], pad 288->296
    __shared__ unsigned short pLDS[64 * 296];  // [m][k]

    // XCD swizzle: neighbors in (h,w) share XCD for xT L2 reuse.
    const int bid = blockIdx.x;
    const int s = bid >> 7;
    const int hg = bid & 127;
    const int h = hg >> 2;
    const int w = ((hg & 3) << 3) | s;
    const int loc = h * 32 + w;

    const int tid = threadIdx.x;
    const int lane = tid & 63;
    const int wave = tid >> 6;
    const int quad = lane >> 4;
    const int l16 = lane & 15;
    const int wm = wave >> 1, wn = wave & 1;  // 2x2 wave grid over (m32, o32)

    // ---- stage weight (64*288 f32, contiguous) -> wLDS bf16 ----
    const float* wg = weight + (size_t)loc * 18432;
#pragma unroll
    for (int i = 0; i < 18; ++i) {
        const int f4i = tid + i * 256;
        const float4 v = reinterpret_cast<const float4*>(wg)[f4i];
        const int o = f4i / 72;
        const int k4 = (f4i - o * 72) * 4;
        ushort4b u;
        u.x = f2bf(v.x); u.y = f2bf(v.y); u.z = f2bf(v.z); u.w = f2bf(v.w);
        *reinterpret_cast<ushort4b*>(&wLDS[o * 296 + k4]) = u;
    }

    // ---- precompute xT offsets for this thread's 72 k's (OOB folded to zero-row) ----
    int xoff[18][4];
#pragma unroll
    for (int j = 0; j < 18; ++j) {
        const int kq = wave + 4 * j;
#pragma unroll
        for (int ii = 0; ii < 4; ++ii) {
            const int k = kq * 4 + ii;
            const int c = k / 9;
            const int r9 = k - c * 9;
            const int yy = r9 / 3;
            const int q = r9 - yy * 3;
            const int y = h - 1 + yy;
            const int xc = w - 1 + q;
            const bool valid = ((unsigned)y < 32u) && ((unsigned)xc < 32u);
            const int off = valid ? ((c * 32 + y) * 32 + xc) * 320 : XT_ELEMS;
            xoff[j][ii] = off + lane;
        }
    }

    __syncthreads();

    // ---- B-fragments in registers for the whole m-loop (weight read once) ----
    short8 bfr[2][9];
#pragma unroll
    for (int tni = 0; tni < 2; ++tni) {
        const int o = (wn * 2 + tni) * 16 + l16;
#pragma unroll
        for (int kt = 0; kt < 9; ++kt)
            bfr[tni][kt] = *reinterpret_cast<const short8*>(&wLDS[o * 296 + kt * 32 + quad * 8]);
    }

    float* os = out_s + (size_t)loc * 20480;

    for (int mt = 0; mt < 5; ++mt) {
        const int mb = mt * 64;
        __syncthreads();  // pLDS WAR vs previous iteration's A-frag reads
#pragma unroll
        for (int j = 0; j < 18; ++j) {
            ushort4b u;
            u.x = xT[xoff[j][0] + mb];
            u.y = xT[xoff[j][1] + mb];
            u.z = xT[xoff[j][2] + mb];
            u.w = xT[xoff[j][3] + mb];
            const int kq = wave + 4 * j;
            *reinterpret_cast<ushort4b*>(&pLDS[lane * 296 + kq * 4]) = u;
        }
        __syncthreads();

        f32x4 acc[2][2] = {};
#pragma unroll
        for (int kt = 0; kt < 9; ++kt) {
            const short8 a0 = *reinterpret_cast<const short8*>(
                &pLDS[((wm * 2 + 0) * 16 + l16) * 296 + kt * 32 + quad * 8]);
            const short8 a1 = *reinterpret_cast<const short8*>(
                &pLDS[((wm * 2 + 1) * 16 + l16) * 296 + kt * 32 + quad * 8]);
            acc[0][0] = __builtin_amdgcn_mfma_f32_16x16x32_bf16(a0, bfr[0][kt], acc[0][0], 0, 0, 0);
            acc[0][1] = __builtin_amdgcn_mfma_f32_16x16x32_bf16(a0, bfr[1][kt], acc[0][1], 0, 0, 0);
            acc[1][0] = __builtin_amdgcn_mfma_f32_16x16x32_bf16(a1, bfr[0][kt], acc[1][0], 0, 0, 0);
            acc[1][1] = __builtin_amdgcn_mfma_f32_16x16x32_bf16(a1, bfr[1][kt], acc[1][1], 0, 0, 0);
        }

        // D layout: row m = quad*4 + r, col o = l16. Stores: 4x64B full lines/instr.
#pragma unroll
        for (int tmi = 0; tmi < 2; ++tmi)
#pragma unroll
            for (int tni = 0; tni < 2; ++tni) {
                const int o = (wn * 2 + tni) * 16 + l16;
#pragma unroll
                for (int r = 0; r < 4; ++r) {
                    const int m = mb + (wm * 2 + tmi) * 16 + quad * 4 + r;
                    os[m * 64 + o] = acc[tmi][tni][r];
                }
            }
    }
}

// ---- kernel 3: out_s[loc][m*64+o] -> out[(m*64+o)*1024+loc], bias fused.
// Block = (m, loc-tile); mo-tile is 64-aligned so m (and cat) are block-constant.
__global__ __launch_bounds__(256) void VecLocal2d_outT(const float* __restrict__ out_s,
                                                       const float* __restrict__ bias,
                                                       float* __restrict__ out) {
    __shared__ float tile[64][65];
    const int m = blockIdx.x >> 4;
    const int loc0 = (blockIdx.x & 15) * 64;
    const int t = threadIdx.x;
    const float* src = out_s + (size_t)loc0 * 20480 + m * 64;
#pragma unroll
    for (int p = 0; p < 4; ++p) {
        const int idx = p * 256 + t;      // 0..1023
        const int lr = idx >> 4;          // loc within tile
        const int c4 = (idx & 15) * 4;    // o chunk
        const float4 v = *reinterpret_cast<const float4*>(src + (size_t)lr * 20480 + c4);
        tile[lr][c4 + 0] = v.x; tile[lr][c4 + 1] = v.y;
        tile[lr][c4 + 2] = v.z; tile[lr][c4 + 3] = v.w;
    }
    __syncthreads();
    const int cat = m % 10;
#pragma unroll
    for (int p = 0; p < 4; ++p) {
        const int idx = p * 256 + t;
        const int o = idx >> 4;           // o within tile
        const int l4 = (idx & 15) * 4;    // loc chunk
        const float4 bv = *reinterpret_cast<const float4*>(
            bias + ((size_t)(cat * 64 + o)) * 1024 + loc0 + l4);
        float4 v;
        v.x = tile[l4 + 0][o] + bv.x;
        v.y = tile[l4 + 1][o] + bv.y;
        v.z = tile[l4 + 2][o] + bv.z;
        v.w = tile[l4 + 3][o] + bv.w;
        *reinterpret_cast<float4*>(out + ((size_t)(m * 64 + o)) * 1024 + loc0 + l4) = v;
    }
}

extern "C" void kernel_launch(void* const* d_in, const int* in_sizes, int n_in,
                              void* d_out, int out_size, void* d_ws, size_t ws_size,
                              hipStream_t stream) {
    const float* x = (const float*)d_in[0];
    const float* wgt = (const float*)d_in[1];
    const float* bias = (const float*)d_in[2];
    float* out = (float*)d_out;
    unsigned short* xT = (unsigned short*)d_ws;                       // 21.0 MB
    float* out_s = (float*)((char*)d_ws + OUTS_OFF_BYTES);            // 83.9 MB

    VecLocal2d_xpose<<<2560, 256, 0, stream>>>(x, xT);
    VecLocal2d_main<<<1024, 256, 0, stream>>>(xT, wgt, out_s);
    VecLocal2d_outT<<<5120, 256, 0, stream>>>(out_s, bias, out);
}

// Round 3
// 222.913 us; speedup vs baseline: 2.2941x; 1.1103x over previous
//
#include <hip/hip_runtime.h>
#include <hip/hip_bf16.h>

// VecLocal2d: x[320][32][32][32] f32, weight[32][32][64][288] f32, bias[10][64][1024] f32
// out[320][64][1024] f32.  Per (h,w): out[m,o] = sum_k patch[m,k]*W[o,k] + bias.
//
// R3: k permuted to k' = (dy*3+dx)*32 + c, and x transposed to xT2[yx][m][c] bf16.
// A-fragments are then direct 16B global loads (1KB/wave) -> no pLDS, no barriers in
// the m-loop. Weight staged once to LDS with the same k-permutation; B-frags in VGPRs.

typedef __attribute__((ext_vector_type(8))) short short8;
typedef __attribute__((ext_vector_type(4))) float f32x4;
typedef __attribute__((ext_vector_type(4))) unsigned short ushort4b;

#define XT2_ELEMS 10485760             // 1024 yx * 320 m * 32 c
#define ZSLAB_ELEMS 10240              // 320 m * 32 c zero slab for OOB taps
#define OUTS_OFF_BYTES 20992000        // (XT2_ELEMS + ZSLAB_ELEMS)*2 = 20,992,000 B

__device__ __forceinline__ unsigned short f2bf(float f) {
    __hip_bfloat16 b = __float2bfloat16(f);
    return __builtin_bit_cast(unsigned short, b);
}

// ---- kernel 1: x[mc][yx] f32 -> xT2[yx][mc] bf16  (10240 x 1024 transpose)
__global__ __launch_bounds__(256) void VecLocal2d_xpose(const float* __restrict__ x,
                                                        unsigned short* __restrict__ xT2) {
    __shared__ unsigned short tile[64][68];  // row = 136 B (8B-aligned for b64 writes)
    if (blockIdx.x == 0) {  // zero slab for out-of-bounds patch taps
#pragma unroll
        for (int j = 0; j < 20; ++j)
            reinterpret_cast<unsigned int*>(xT2 + XT2_ELEMS)[threadIdx.x + j * 256] = 0u;
    }
    const int mcb = blockIdx.x >> 4;   // 160 tiles over mc
    const int yxb = blockIdx.x & 15;   // 16 tiles over yx
    const int t = threadIdx.x;
    const int g = t >> 4;              // 0..15
    const int l4 = (t & 15) * 4;
#pragma unroll
    for (int p = 0; p < 4; ++p) {
        const int ml = g + p * 16;     // mc-local row
        const float4 v = *reinterpret_cast<const float4*>(
            x + (size_t)(mcb * 64 + ml) * 1024 + yxb * 64 + l4);
        ushort4b u;
        u.x = f2bf(v.x); u.y = f2bf(v.y); u.z = f2bf(v.z); u.w = f2bf(v.w);
        *reinterpret_cast<ushort4b*>(&tile[ml][l4]) = u;
    }
    __syncthreads();
#pragma unroll
    for (int p = 0; p < 4; ++p) {
        const int yl = g + p * 16;     // yx-local row
        ushort4b u;
        u.x = tile[l4 + 0][yl];
        u.y = tile[l4 + 1][yl];
        u.z = tile[l4 + 2][yl];
        u.w = tile[l4 + 3][yl];
        *reinterpret_cast<ushort4b*>(xT2 + (size_t)(yxb * 64 + yl) * 10240 + mcb * 64 + l4) = u;
    }
}

// ---- kernel 2: main GEMM per location; A-frags straight from global, no inner barriers
__global__ __launch_bounds__(256, 4) void VecLocal2d_main(const unsigned short* __restrict__ xT2,
                                                          const float* __restrict__ weight,
                                                          float* __restrict__ out_s) {
    __shared__ unsigned short wLDS[64 * 296];  // [o][k'], k' = (dy*3+dx)*32 + c, pad->296

    // XCD swizzle: neighbors in (h,w) share XCD for xT2 L2 reuse.
    const int bid = blockIdx.x;
    const int s = bid >> 7;
    const int hg = bid & 127;
    const int h = hg >> 2;
    const int w = ((hg & 3) << 3) | s;
    const int loc = h * 32 + w;

    const int tid = threadIdx.x;
    const int lane = tid & 63;
    const int wave = tid >> 6;
    const int quad = lane >> 4;
    const int l16 = lane & 15;
    const int wm = wave >> 1, wn = wave & 1;  // 2x2 wave grid over (m32, o32)

    // ---- stage weight (64*288 f32, contiguous reads) -> wLDS bf16, k-permuted ----
    const float* wg = weight + (size_t)loc * 18432;
#pragma unroll
    for (int i = 0; i < 18; ++i) {
        const int f4i = tid + i * 256;
        const float4 v = reinterpret_cast<const float4*>(wg)[f4i];
        const int o = f4i / 72;
        const int kbase = (f4i - o * 72) * 4;
        const float vv[4] = {v.x, v.y, v.z, v.w};
#pragma unroll
        for (int e = 0; e < 4; ++e) {
            const int k = kbase + e;       // original k = c*9 + r
            const int c = k / 9;
            const int r = k - c * 9;
            wLDS[o * 296 + r * 32 + c] = f2bf(vv[e]);
        }
    }

    // ---- 9 neighbor base offsets (block-uniform -> SGPRs); OOB -> zero slab ----
    int base[9];
#pragma unroll
    for (int dy = 0; dy < 3; ++dy)
#pragma unroll
        for (int dx = 0; dx < 3; ++dx) {
            const int y = h - 1 + dy;
            const int xc = w - 1 + dx;
            const bool valid = ((unsigned)y < 32u) && ((unsigned)xc < 32u);
            base[dy * 3 + dx] = valid ? (y * 32 + xc) * 10240 : XT2_ELEMS;
        }

    __syncthreads();

    // ---- B-fragments in registers for the whole m-loop (weight read once) ----
    short8 bfr[2][9];
#pragma unroll
    for (int tni = 0; tni < 2; ++tni) {
        const int o = (wn * 2 + tni) * 16 + l16;
#pragma unroll
        for (int kt = 0; kt < 9; ++kt)
            bfr[tni][kt] = *reinterpret_cast<const short8*>(&wLDS[o * 296 + kt * 32 + quad * 8]);
    }

    const int laneA = (wm * 32 + l16) * 32 + quad * 8;  // + tmi*512 + mt*2048
    float* os = out_s + (size_t)loc * 20480;

    for (int mt = 0; mt < 5; ++mt) {
        const int moff = laneA + mt * 2048;
        f32x4 acc[2][2] = {};
#pragma unroll
        for (int kt = 0; kt < 9; ++kt) {
            const short8 a0 = *reinterpret_cast<const short8*>(xT2 + base[kt] + moff);
            const short8 a1 = *reinterpret_cast<const short8*>(xT2 + base[kt] + moff + 512);
            acc[0][0] = __builtin_amdgcn_mfma_f32_16x16x32_bf16(a0, bfr[0][kt], acc[0][0], 0, 0, 0);
            acc[0][1] = __builtin_amdgcn_mfma_f32_16x16x32_bf16(a0, bfr[1][kt], acc[0][1], 0, 0, 0);
            acc[1][0] = __builtin_amdgcn_mfma_f32_16x16x32_bf16(a1, bfr[0][kt], acc[1][0], 0, 0, 0);
            acc[1][1] = __builtin_amdgcn_mfma_f32_16x16x32_bf16(a1, bfr[1][kt], acc[1][1], 0, 0, 0);
        }

        // D layout: row m = quad*4 + r, col o = l16. Stores: 4x64B full lines/instr.
#pragma unroll
        for (int tmi = 0; tmi < 2; ++tmi)
#pragma unroll
            for (int tni = 0; tni < 2; ++tni) {
                const int o = (wn * 2 + tni) * 16 + l16;
#pragma unroll
                for (int r = 0; r < 4; ++r) {
                    const int m = mt * 64 + (wm * 2 + tmi) * 16 + quad * 4 + r;
                    os[m * 64 + o] = acc[tmi][tni][r];
                }
            }
    }
}

// ---- kernel 3: out_s[loc][m*64+o] -> out[(m*64+o)*1024+loc], bias fused.
__global__ __launch_bounds__(256) void VecLocal2d_outT(const float* __restrict__ out_s,
                                                       const float* __restrict__ bias,
                                                       float* __restrict__ out) {
    __shared__ float tile[64][65];
    const int m = blockIdx.x >> 4;
    const int loc0 = (blockIdx.x & 15) * 64;
    const int t = threadIdx.x;
    const float* src = out_s + (size_t)loc0 * 20480 + m * 64;
#pragma unroll
    for (int p = 0; p < 4; ++p) {
        const int idx = p * 256 + t;
        const int lr = idx >> 4;          // loc within tile
        const int c4 = (idx & 15) * 4;    // o chunk
        const float4 v = *reinterpret_cast<const float4*>(src + (size_t)lr * 20480 + c4);
        tile[lr][c4 + 0] = v.x; tile[lr][c4 + 1] = v.y;
        tile[lr][c4 + 2] = v.z; tile[lr][c4 + 3] = v.w;
    }
    __syncthreads();
    const int cat = m % 10;
#pragma unroll
    for (int p = 0; p < 4; ++p) {
        const int idx = p * 256 + t;
        const int o = idx >> 4;           // o within tile
        const int l4 = (idx & 15) * 4;    // loc chunk
        const float4 bv = *reinterpret_cast<const float4*>(
            bias + ((size_t)(cat * 64 + o)) * 1024 + loc0 + l4);
        float4 v;
        v.x = tile[l4 + 0][o] + bv.x;
        v.y = tile[l4 + 1][o] + bv.y;
        v.z = tile[l4 + 2][o] + bv.z;
        v.w = tile[l4 + 3][o] + bv.w;
        *reinterpret_cast<float4*>(out + ((size_t)(m * 64 + o)) * 1024 + loc0 + l4) = v;
    }
}

extern "C" void kernel_launch(void* const* d_in, const int* in_sizes, int n_in,
                              void* d_out, int out_size, void* d_ws, size_t ws_size,
                              hipStream_t stream) {
    const float* x = (const float*)d_in[0];
    const float* wgt = (const float*)d_in[1];
    const float* bias = (const float*)d_in[2];
    float* out = (float*)d_out;
    unsigned short* xT2 = (unsigned short*)d_ws;                      // 21.0 MB (+20KB slab)
    float* out_s = (float*)((char*)d_ws + OUTS_OFF_BYTES);            // 83.9 MB

    VecLocal2d_xpose<<<2560, 256, 0, stream>>>(x, xT2);
    VecLocal2d_main<<<1024, 256, 0, stream>>>(xT2, wgt, out_s);
    VecLocal2d_outT<<<5120, 256, 0, stream>>>(out_s, bias, out);
}